// Round 7
// baseline (406.323 us; speedup 1.0000x reference)
//
#include <hip/hip_runtime.h>

#define DIN 128
#define DOUT 64
#define SH 8            // nodes per bucket = 256
#define CAP 8192        // slots per bucket (avg ~4096, +64 sigma headroom)
#define BMAX 512
#define XS_STRIDE (DIN + 4)
#define TILE_SH 15      // src-tile = 32768 nodes = 4.0 MB bf16 rows (~one XCD L2)
#define NTILE 4
#define RPW 13          // rows per wave (8192 waves * 13 >= 100000)
#define GBLK 2048       // persistent-ish grid: 8 blocks/CU

typedef unsigned short ushort_t;

__device__ __forceinline__ ushort_t f2bf(float f) {
    union { float f; unsigned u; } v; v.f = f;
    unsigned r = v.u + 0x7FFF + ((v.u >> 16) & 1);   // round-nearest-even
    return (ushort_t)(r >> 16);
}
__device__ __forceinline__ float bf2f(ushort_t h) {
    union { unsigned u; float f; } v; v.u = ((unsigned)h) << 16;
    return v.f;
}

// ---------- pass A: bin edges by dst>>SH, packed (ldst<<17)|src ----------
__global__ __launch_bounds__(256) void bin_kernel(const int* __restrict__ src,
                                                  const int* __restrict__ dst,
                                                  int* __restrict__ cursor,
                                                  int* __restrict__ binned, int E, int B) {
    __shared__ int hist_s[BMAX], gbase_s[BMAX], cur_s[BMAX];
    for (int i = threadIdx.x; i < B; i += 256) { hist_s[i] = 0; cur_s[i] = 0; }
    __syncthreads();
    int e0 = blockIdx.x * 4096;
    int e1 = min(e0 + 4096, E);
    for (int e = e0 + threadIdx.x; e < e1; e += 256)
        atomicAdd(&hist_s[dst[e] >> SH], 1);
    __syncthreads();
    for (int b = threadIdx.x; b < B; b += 256) {
        int h = hist_s[b];
        gbase_s[b] = h ? atomicAdd(&cursor[b], h) : 0;
    }
    __syncthreads();
    for (int e = e0 + threadIdx.x; e < e1; e += 256) {
        int d = dst[e], s = src[e];
        int b = d >> SH;
        int off  = atomicAdd(&cur_s[b], 1);
        int slot = gbase_s[b] + off;
        if (slot < (b + 1) * CAP)
            binned[slot] = ((d & ((1 << SH) - 1)) << 17) | s;
    }
}

__global__ void init_cursor_kernel(int* cursor, int B, int* csr_pad) {
    int b = blockIdx.x * 256 + threadIdx.x;
    if (b < B) cursor[b] = b * CAP;
    if (b < 16) csr_pad[b] = 0;
}

// exclusive scan of bucket counts -> bucket_base; starts[4N] = total sentinel
__global__ __launch_bounds__(BMAX) void bucket_scan_kernel(const int* __restrict__ cursor,
                                                           int* __restrict__ bucket_base,
                                                           int* __restrict__ starts,
                                                           int B, int N) {
    __shared__ int sh[BMAX];
    int t = threadIdx.x;
    int c = 0;
    if (t < B) { c = cursor[t] - t * CAP; if (c > CAP) c = CAP; }
    sh[t] = c;
    __syncthreads();
    for (int off = 1; off < BMAX; off <<= 1) {
        int v = (t >= off) ? sh[t - off] : 0;
        __syncthreads();
        sh[t] += v;
        __syncthreads();
    }
    if (t < B) bucket_base[t] = sh[t] - c;  // exclusive
    if (t == 0) starts[4 * N] = sh[B - 1];  // sentinel (== total)
}

// ---------- pass B: per-bucket CSR build, src-TILED per row ----------
// key = (local_node<<2) | (src>>TILE_SH). Emits starts[node*4+t] and dinv.
__global__ __launch_bounds__(256) void csr_kernel(const int* __restrict__ binned,
                                                  const int* __restrict__ cursor,
                                                  const int* __restrict__ bucket_base,
                                                  int* __restrict__ starts,
                                                  float* __restrict__ dinv,
                                                  int* __restrict__ csr_src, int N) {
    __shared__ int cnt_s[1024], cur_s[1024], sc_s[256];
    int b = blockIdx.x;
    int t = threadIdx.x;
    int ecnt = cursor[b] - b * CAP; if (ecnt > CAP) ecnt = CAP;
    int base = bucket_base[b];
    const int* eb = binned + (size_t)b * CAP;
    for (int i = t; i < 1024; i += 256) cnt_s[i] = 0;
    __syncthreads();
    for (int i = t; i < ecnt; i += 256) {
        int p = eb[i];
        int key = ((p >> 17) << 2) | ((p & 0x1FFFF) >> TILE_SH);
        atomicAdd(&cnt_s[key], 1);
    }
    __syncthreads();
    int c0 = cnt_s[4*t+0], c1 = cnt_s[4*t+1], c2 = cnt_s[4*t+2], c3 = cnt_s[4*t+3];
    int mysum = c0 + c1 + c2 + c3;            // row degree
    sc_s[t] = mysum;
    __syncthreads();
    for (int off = 1; off < 256; off <<= 1) {
        int v = (t >= off) ? sc_s[t - off] : 0;
        __syncthreads();
        sc_s[t] += v;
        __syncthreads();
    }
    int excl = sc_s[t] - mysum;
    int node = (b << SH) + t;
    int s0 = base + excl, s1 = s0 + c0, s2 = s1 + c1, s3 = s2 + c2;
    if (node < N) {
        dinv[node] = rsqrtf((float)mysum + 1.0f);  // +1 = self loop
        starts[node*4+0] = s0; starts[node*4+1] = s1;
        starts[node*4+2] = s2; starts[node*4+3] = s3;
    }
    cur_s[4*t+0] = s0; cur_s[4*t+1] = s1; cur_s[4*t+2] = s2; cur_s[4*t+3] = s3;
    __syncthreads();
    for (int i = t; i < ecnt; i += 256) {
        int p = eb[i];
        int key = ((p >> 17) << 2) | ((p & 0x1FFFF) >> TILE_SH);
        int slot = atomicAdd(&cur_s[key], 1);
        csr_src[slot] = p & 0x1FFFF;
    }
}

// ---------- projection: y0' = dinv * (x @ W^T), stored bf16 ----------
__global__ __launch_bounds__(256) void gemm_kernel(const float* __restrict__ x,
                                                   const float* __restrict__ W,
                                                   const float* __restrict__ dinv,
                                                   ushort_t* __restrict__ yb, int N) {
    __shared__ float Ws[DIN * DOUT];
    __shared__ float xs[64 * XS_STRIDE];
    int tid  = threadIdx.x;
    int row0 = blockIdx.x * 64;

    for (int j = tid; j < DIN * DOUT; j += 256)
        Ws[j] = W[(j & 63) * DIN + (j >> 6)];

    for (int j = tid; j < 64 * DIN / 4; j += 256) {
        int r  = j >> 5;
        int c4 = (j & 31) * 4;
        int grow = row0 + r;
        float4 v = {0.f, 0.f, 0.f, 0.f};
        if (grow < N) v = *(const float4*)&x[(size_t)grow * DIN + c4];
        *(float4*)&xs[r * XS_STRIDE + c4] = v;
    }
    __syncthreads();

    int g    = tid & 15;
    int rgl  = (tid >> 4) & 3;
    int wave = tid >> 6;
    int rloc = wave * 16 + rgl * 4;

    float4 acc[4] = {};
    for (int kk = 0; kk < DIN; kk += 4) {
        float4 wv0 = *(const float4*)&Ws[(kk + 0) * DOUT + g * 4];
        float4 wv1 = *(const float4*)&Ws[(kk + 1) * DOUT + g * 4];
        float4 wv2 = *(const float4*)&Ws[(kk + 2) * DOUT + g * 4];
        float4 wv3 = *(const float4*)&Ws[(kk + 3) * DOUT + g * 4];
        #pragma unroll
        for (int r = 0; r < 4; ++r) {
            float4 xv = *(const float4*)&xs[(rloc + r) * XS_STRIDE + kk];
            acc[r].x += xv.x * wv0.x + xv.y * wv1.x + xv.z * wv2.x + xv.w * wv3.x;
            acc[r].y += xv.x * wv0.y + xv.y * wv1.y + xv.z * wv2.y + xv.w * wv3.y;
            acc[r].z += xv.x * wv0.z + xv.y * wv1.z + xv.z * wv2.z + xv.w * wv3.z;
            acc[r].w += xv.x * wv0.w + xv.y * wv1.w + xv.z * wv2.w + xv.w * wv3.w;
        }
    }
    #pragma unroll
    for (int r = 0; r < 4; ++r) {
        int grow = row0 + rloc + r;
        if (grow < N) {
            float dv = dinv[grow];
            ushort4 o;
            o.x = f2bf(acc[r].x * dv); o.y = f2bf(acc[r].y * dv);
            o.z = f2bf(acc[r].z * dv); o.w = f2bf(acc[r].w * dv);
            *(ushort4*)&yb[(size_t)grow * DOUT + g * 4] = o;
        }
    }
}

// ---------- src-tiled pull-gather: wave owns RPW rows, tiles walked in order ----------
// All waves process tile 0 first, then 1,2,3 -> XCD L2 working set ~ one 4MB tile.
template <int FINAL>
__global__ __launch_bounds__(256, 8) void gather_kernel(const int* __restrict__ starts,
                                                        const int* __restrict__ csr_src,
                                                        const float* __restrict__ dinv,
                                                        const ushort_t* __restrict__ yin,
                                                        const float* __restrict__ bias,
                                                        ushort_t* __restrict__ yout,
                                                        float* __restrict__ out,
                                                        float* __restrict__ emb, int N) {
    int gw   = blockIdx.x * 4 + (threadIdx.x >> 6);
    int lane = threadIdx.x & 63;
    int r0   = gw * RPW;
    if (r0 >= N) return;
    const ushort_t* ylane = yin + lane;

    float acc[RPW];
    #pragma unroll
    for (int k = 0; k < RPW; ++k) {
        int r = r0 + k;
        acc[k] = (r < N) ? bf2f(yin[(size_t)r * DOUT + lane]) : 0.f;  // self loop
    }

    for (int t = 0; t < NTILE; ++t) {
        #pragma unroll
        for (int k = 0; k < RPW; ++k) {
            int r = r0 + k;
            if (r < N) {
                int e0 = __builtin_amdgcn_readfirstlane(starts[4 * r + t]);
                int e1 = __builtin_amdgcn_readfirstlane(starts[4 * r + t + 1]);
                float a = 0.f;
                for (int bb = e0; bb < e1; bb += 8) {
                    float v[8];
                    #pragma unroll
                    for (int j = 0; j < 8; ++j) {
                        int ij = (bb + j < e1) ? bb + j : e0;   // clamp: dup line, no new miss
                        int s = __builtin_amdgcn_readfirstlane(csr_src[ij]);
                        float f = bf2f(ylane[(size_t)s * DOUT]);
                        v[j] = (bb + j < e1) ? f : 0.f;
                    }
                    a += ((v[0] + v[1]) + (v[2] + v[3])) + ((v[4] + v[5]) + (v[6] + v[7]));
                }
                acc[k] += a;
            }
        }
    }

    #pragma unroll
    for (int k = 0; k < RPW; ++k) {
        int r = r0 + k;
        if (r >= N) continue;
        float dv = dinv[r];
        if (!FINAL) {
            yout[(size_t)r * DOUT + lane] = f2bf(dv * dv * acc[k]);
        } else {
            float e = dv * acc[k] + bias[lane];
            emb[(size_t)r * DOUT + lane] = e;
            float m = e;
            for (int o = 32; o; o >>= 1) m = fmaxf(m, __shfl_xor(m, o, 64));
            float ex = expf(e - m);
            float ss = ex;
            for (int o = 32; o; o >>= 1) ss += __shfl_xor(ss, o, 64);
            out[(size_t)r * DOUT + lane] = e - m - logf(ss);
        }
    }
}

extern "C" void kernel_launch(void* const* d_in, const int* in_sizes, int n_in,
                              void* d_out, int out_size, void* d_ws, size_t ws_size,
                              hipStream_t stream) {
    const float* x    = (const float*)d_in[0];
    const int*   edge = (const int*)d_in[1];
    const float* W    = (const float*)d_in[2];
    const float* b    = (const float*)d_in[3];

    const int N = in_sizes[0] / DIN;   // 100000
    const int E = in_sizes[1] / 2;     // 1600000
    const int* src = edge;
    const int* dst = edge + E;

    float* out_ptr = (float*)d_out;                // [N,64] log_softmax
    float* emb_ptr = out_ptr + (size_t)N * DOUT;   // [N,64] emb

    const int B = (N + (1 << SH) - 1) >> SH;       // 391 buckets

    // workspace (~34 MB):
    //   cursor[512] | bucket_base[512] | starts[4N+1] | dinv[N] | csr_src[E+16] |
    //   arena: binned[B*CAP] ints (CSR build) aliased with y0b,y1b bf16 (gathers)
    int*     cursor      = (int*)d_ws;
    int*     bucket_base = cursor + BMAX;
    int*     starts      = bucket_base + BMAX;
    float*   dinv        = (float*)(starts + 4 * N + 1);
    int*     csr_src     = (int*)(dinv + N);
    int*     arena       = csr_src + E + 16;
    int*     binned      = arena;
    ushort_t* y0b        = (ushort_t*)arena;        // aliases binned (dead after csr_kernel)
    ushort_t* y1b        = y0b + (size_t)N * DOUT;

    // 1. tiled CSR by dst + dinv
    init_cursor_kernel<<<(B + 255) / 256, 256, 0, stream>>>(cursor, B, csr_src + E);
    bin_kernel<<<(E + 4095) / 4096, 256, 0, stream>>>(src, dst, cursor, binned, E, B);
    bucket_scan_kernel<<<1, BMAX, 0, stream>>>(cursor, bucket_base, starts, B, N);
    csr_kernel<<<B, 256, 0, stream>>>(binned, cursor, bucket_base, starts, dinv, csr_src, N);

    // 2. project + pre-scale: y0' = dinv * (x @ W^T)   (bf16)
    gemm_kernel<<<(N + 63) / 64, 256, 0, stream>>>(x, W, dinv, y0b, N);

    // 3. hop 1 (src-tiled): y1' = dinv^2 * (y0'[row] + sum y0'[src])
    gather_kernel<0><<<GBLK, 256, 0, stream>>>(starts, csr_src, dinv, y0b, b,
                                               y1b, nullptr, nullptr, N);

    // 4. hop 2 (src-tiled) + bias + log_softmax, fused
    gather_kernel<1><<<GBLK, 256, 0, stream>>>(starts, csr_src, dinv, y1b, b,
                                               nullptr, out_ptr, emb_ptr, N);
}

// Round 8
// 228.576 us; speedup vs baseline: 1.7776x; 1.7776x over previous
//
#include <hip/hip_runtime.h>

#define DIN 128
#define DOUT 64
#define SH 8            // nodes per bucket = 256
#define CAP 8192        // slots per bucket (avg ~4096, +64 sigma headroom)
#define BMAX 512
#define XS_STRIDE (DIN + 4)

typedef unsigned short ushort_t;

__device__ __forceinline__ ushort_t f2bf(float f) {
    union { float f; unsigned u; } v; v.f = f;
    unsigned r = v.u + 0x7FFF + ((v.u >> 16) & 1);   // round-nearest-even
    return (ushort_t)(r >> 16);
}

// ---------- pass A: bin edges by dst>>SH, packed (ldst<<17)|src ----------
__global__ __launch_bounds__(256) void bin_kernel(const int* __restrict__ src,
                                                  const int* __restrict__ dst,
                                                  int* __restrict__ cursor,
                                                  int* __restrict__ binned, int E, int B) {
    __shared__ int hist_s[BMAX], gbase_s[BMAX], cur_s[BMAX];
    for (int i = threadIdx.x; i < B; i += 256) { hist_s[i] = 0; cur_s[i] = 0; }
    __syncthreads();
    int e0 = blockIdx.x * 4096;
    int e1 = min(e0 + 4096, E);
    for (int e = e0 + threadIdx.x; e < e1; e += 256)
        atomicAdd(&hist_s[dst[e] >> SH], 1);
    __syncthreads();
    for (int b = threadIdx.x; b < B; b += 256) {
        int h = hist_s[b];
        gbase_s[b] = h ? atomicAdd(&cursor[b], h) : 0;
    }
    __syncthreads();
    for (int e = e0 + threadIdx.x; e < e1; e += 256) {
        int d = dst[e], s = src[e];
        int b = d >> SH;
        int off  = atomicAdd(&cur_s[b], 1);
        int slot = gbase_s[b] + off;
        if (slot < (b + 1) * CAP)
            binned[slot] = ((d & ((1 << SH) - 1)) << 17) | s;
    }
}

__global__ void init_cursor_kernel(int* cursor, int B, int* csr_pad) {
    int b = blockIdx.x * 256 + threadIdx.x;
    if (b < B) cursor[b] = b * CAP;
    if (b < 16) csr_pad[b] = 0;
}

// exclusive scan of bucket counts -> bucket_base; row_ptr[N] = total
__global__ __launch_bounds__(BMAX) void bucket_scan_kernel(const int* __restrict__ cursor,
                                                           int* __restrict__ bucket_base,
                                                           int* __restrict__ row_ptr,
                                                           int B, int N) {
    __shared__ int sh[BMAX];
    int t = threadIdx.x;
    int c = 0;
    if (t < B) { c = cursor[t] - t * CAP; if (c > CAP) c = CAP; }
    sh[t] = c;
    __syncthreads();
    for (int off = 1; off < BMAX; off <<= 1) {
        int v = (t >= off) ? sh[t - off] : 0;
        __syncthreads();
        sh[t] += v;
        __syncthreads();
    }
    if (t < B) bucket_base[t] = sh[t] - c;  // exclusive
    if (t == 0) row_ptr[N] = sh[B - 1];     // total (== E)
}

// ---------- pass B: per-bucket CSR build + row_ptr + dinv ----------
__global__ __launch_bounds__(256) void csr_kernel(const int* __restrict__ binned,
                                                  const int* __restrict__ cursor,
                                                  const int* __restrict__ bucket_base,
                                                  int* __restrict__ row_ptr,
                                                  float* __restrict__ dinv,
                                                  int* __restrict__ csr_src, int N) {
    __shared__ int cnt_s[256], off_s[256];
    int b = blockIdx.x;
    int t = threadIdx.x;
    int ecnt = cursor[b] - b * CAP; if (ecnt > CAP) ecnt = CAP;
    int base = bucket_base[b];
    const int* eb = binned + (size_t)b * CAP;
    cnt_s[t] = 0;
    __syncthreads();
    for (int i = t; i < ecnt; i += 256)
        atomicAdd(&cnt_s[eb[i] >> 17], 1);
    __syncthreads();
    int myc = cnt_s[t];
    off_s[t] = myc;
    __syncthreads();
    for (int off = 1; off < 256; off <<= 1) {
        int v = (t >= off) ? off_s[t - off] : 0;
        __syncthreads();
        off_s[t] += v;
        __syncthreads();
    }
    int excl = off_s[t] - myc;
    int node = (b << SH) + t;
    if (node < N) {
        row_ptr[node] = base + excl;
        dinv[node] = rsqrtf((float)myc + 1.0f);  // +1 = self loop
    }
    __syncthreads();
    off_s[t] = base + excl;   // global write cursor for this node
    __syncthreads();
    for (int i = t; i < ecnt; i += 256) {
        int p = eb[i];
        int slot = atomicAdd(&off_s[p >> 17], 1);
        csr_src[slot] = p & 0x1FFFF;
    }
}

// ---------- projection: y0' = dinv * (x @ W^T), stored bf16 ----------
__global__ __launch_bounds__(256) void gemm_kernel(const float* __restrict__ x,
                                                   const float* __restrict__ W,
                                                   const float* __restrict__ dinv,
                                                   ushort_t* __restrict__ yb, int N) {
    __shared__ float Ws[DIN * DOUT];
    __shared__ float xs[64 * XS_STRIDE];
    int tid  = threadIdx.x;
    int row0 = blockIdx.x * 64;

    for (int j = tid; j < DIN * DOUT; j += 256)
        Ws[j] = W[(j & 63) * DIN + (j >> 6)];

    for (int j = tid; j < 64 * DIN / 4; j += 256) {
        int r  = j >> 5;
        int c4 = (j & 31) * 4;
        int grow = row0 + r;
        float4 v = {0.f, 0.f, 0.f, 0.f};
        if (grow < N) v = *(const float4*)&x[(size_t)grow * DIN + c4];
        *(float4*)&xs[r * XS_STRIDE + c4] = v;
    }
    __syncthreads();

    int g    = tid & 15;
    int rgl  = (tid >> 4) & 3;
    int wave = tid >> 6;
    int rloc = wave * 16 + rgl * 4;

    float4 acc[4] = {};
    for (int kk = 0; kk < DIN; kk += 4) {
        float4 wv0 = *(const float4*)&Ws[(kk + 0) * DOUT + g * 4];
        float4 wv1 = *(const float4*)&Ws[(kk + 1) * DOUT + g * 4];
        float4 wv2 = *(const float4*)&Ws[(kk + 2) * DOUT + g * 4];
        float4 wv3 = *(const float4*)&Ws[(kk + 3) * DOUT + g * 4];
        #pragma unroll
        for (int r = 0; r < 4; ++r) {
            float4 xv = *(const float4*)&xs[(rloc + r) * XS_STRIDE + kk];
            acc[r].x += xv.x * wv0.x + xv.y * wv1.x + xv.z * wv2.x + xv.w * wv3.x;
            acc[r].y += xv.x * wv0.y + xv.y * wv1.y + xv.z * wv2.y + xv.w * wv3.y;
            acc[r].z += xv.x * wv0.z + xv.y * wv1.z + xv.z * wv2.z + xv.w * wv3.z;
            acc[r].w += xv.x * wv0.w + xv.y * wv1.w + xv.z * wv2.w + xv.w * wv3.w;
        }
    }
    #pragma unroll
    for (int r = 0; r < 4; ++r) {
        int grow = row0 + rloc + r;
        if (grow < N) {
            float dv = dinv[grow];
            ushort4 o;
            o.x = f2bf(acc[r].x * dv); o.y = f2bf(acc[r].y * dv);
            o.z = f2bf(acc[r].z * dv); o.w = f2bf(acc[r].w * dv);
            *(ushort4*)&yb[(size_t)grow * DOUT + g * 4] = o;
        }
    }
}

// unpack 4 dwords (8 bf16) and add into acc[8]
__device__ __forceinline__ void add_unpack(float* acc, uint4 v) {
    unsigned u[4] = {v.x, v.y, v.z, v.w};
    #pragma unroll
    for (int d = 0; d < 4; ++d) {
        union { unsigned u; float f; } lo, hi;
        lo.u = u[d] << 16;
        hi.u = u[d] & 0xFFFF0000u;
        acc[2 * d]     += lo.f;
        acc[2 * d + 1] += hi.f;
    }
}

// ---------- wide pull-gather: wave = 8 slots x 8 feature-blocks ----------
// One dwordx4 load instruction fetches 8 DIFFERENT src rows (8 edges).
// lane = slot*8 + fb; lane accumulates features [fb*8, fb*8+8) of its slot's edges.
// Final: shfl_xor over slot bits (8,16,32) sums the 8 slots.
template <int FINAL>
__global__ __launch_bounds__(256) void gather_kernel(const int* __restrict__ row_ptr,
                                                     const int* __restrict__ csr_src,
                                                     const float* __restrict__ dinv,
                                                     const ushort_t* __restrict__ yin,
                                                     const float* __restrict__ bias,
                                                     ushort_t* __restrict__ yout,
                                                     float* __restrict__ out,
                                                     float* __restrict__ emb, int N) {
    int row = blockIdx.x * 4 + (threadIdx.x >> 6);
    if (row >= N) return;
    int lane = threadIdx.x & 63;
    int fb   = lane & 7;    // feature block: features [fb*8, fb*8+8)
    int slot = lane >> 3;   // edge slot within a batch of 8
    int start = __builtin_amdgcn_readfirstlane(row_ptr[row]);
    int end   = __builtin_amdgcn_readfirstlane(row_ptr[row + 1]);

    float acc[8] = {0.f, 0.f, 0.f, 0.f, 0.f, 0.f, 0.f, 0.f};

    // self loop: all lanes load row's fb-block (8x dup -> same 2 lines), slot 0 accumulates
    {
        uint4 sv = *(const uint4*)(yin + (size_t)row * DOUT + fb * 8);
        if (slot == 0) add_unpack(acc, sv);
    }

    for (int b = start; b < end; b += 8) {
        int ei = b + slot;
        bool valid = ei < end;
        int eidx = valid ? ei : end - 1;           // clamp: dup line, no extra miss
        int s = csr_src[eidx];                     // 32B span per batch
        uint4 v = *(const uint4*)(yin + (size_t)s * DOUT + fb * 8);
        if (valid) add_unpack(acc, v);
    }

    // sum the 8 slots: xor over slot bits
    #pragma unroll
    for (int m = 8; m <= 32; m <<= 1) {
        #pragma unroll
        for (int i = 0; i < 8; ++i) acc[i] += __shfl_xor(acc[i], m, 64);
    }

    float dv = dinv[row];
    if (!FINAL) {
        if (slot == 0) {
            float s2 = dv * dv;
            union { ushort_t us[8]; uint4 u; } o;
            #pragma unroll
            for (int i = 0; i < 8; ++i) o.us[i] = f2bf(acc[i] * s2);
            *(uint4*)(yout + (size_t)row * DOUT + fb * 8) = o.u;
        }
    } else {
        const float4* bp = (const float4*)(bias + fb * 8);
        float4 b0 = bp[0], b1 = bp[1];
        float e[8];
        e[0] = dv * acc[0] + b0.x; e[1] = dv * acc[1] + b0.y;
        e[2] = dv * acc[2] + b0.z; e[3] = dv * acc[3] + b0.w;
        e[4] = dv * acc[4] + b1.x; e[5] = dv * acc[5] + b1.y;
        e[6] = dv * acc[6] + b1.z; e[7] = dv * acc[7] + b1.w;
        float m = e[0];
        #pragma unroll
        for (int i = 1; i < 8; ++i) m = fmaxf(m, e[i]);
        #pragma unroll
        for (int o2 = 1; o2 <= 4; o2 <<= 1) m = fmaxf(m, __shfl_xor(m, o2, 64));
        float ss = 0.f;
        #pragma unroll
        for (int i = 0; i < 8; ++i) ss += expf(e[i] - m);
        #pragma unroll
        for (int o2 = 1; o2 <= 4; o2 <<= 1) ss += __shfl_xor(ss, o2, 64);
        float lg = m + logf(ss);
        if (slot == 0) {
            float4* ep = (float4*)(emb + (size_t)row * DOUT + fb * 8);
            ep[0] = make_float4(e[0], e[1], e[2], e[3]);
            ep[1] = make_float4(e[4], e[5], e[6], e[7]);
            float4* op = (float4*)(out + (size_t)row * DOUT + fb * 8);
            op[0] = make_float4(e[0] - lg, e[1] - lg, e[2] - lg, e[3] - lg);
            op[1] = make_float4(e[4] - lg, e[5] - lg, e[6] - lg, e[7] - lg);
        }
    }
}

extern "C" void kernel_launch(void* const* d_in, const int* in_sizes, int n_in,
                              void* d_out, int out_size, void* d_ws, size_t ws_size,
                              hipStream_t stream) {
    const float* x    = (const float*)d_in[0];
    const int*   edge = (const int*)d_in[1];
    const float* W    = (const float*)d_in[2];
    const float* b    = (const float*)d_in[3];

    const int N = in_sizes[0] / DIN;   // 100000
    const int E = in_sizes[1] / 2;     // 1600000
    const int* src = edge;
    const int* dst = edge + E;

    float* out_ptr = (float*)d_out;                // [N,64] log_softmax
    float* emb_ptr = out_ptr + (size_t)N * DOUT;   // [N,64] emb

    const int B = (N + (1 << SH) - 1) >> SH;       // 391 buckets

    // workspace (~33 MB):
    //   cursor[512] | bucket_base[512] | row_ptr[N+1] | dinv[N] | csr_src[E+16] |
    //   arena: binned[B*CAP] ints (CSR build) aliased with y0b,y1b bf16 (gathers)
    int*     cursor      = (int*)d_ws;
    int*     bucket_base = cursor + BMAX;
    int*     row_ptr     = bucket_base + BMAX;
    float*   dinv        = (float*)(row_ptr + N + 1);
    int*     csr_src     = (int*)(dinv + N);
    int*     arena       = csr_src + E + 16;
    int*     binned      = arena;
    ushort_t* y0b        = (ushort_t*)arena;        // aliases binned (dead after csr_kernel)
    ushort_t* y1b        = y0b + (size_t)N * DOUT;

    // 1. CSR by dst + dinv
    init_cursor_kernel<<<(B + 255) / 256, 256, 0, stream>>>(cursor, B, csr_src + E);
    bin_kernel<<<(E + 4095) / 4096, 256, 0, stream>>>(src, dst, cursor, binned, E, B);
    bucket_scan_kernel<<<1, BMAX, 0, stream>>>(cursor, bucket_base, row_ptr, B, N);
    csr_kernel<<<B, 256, 0, stream>>>(binned, cursor, bucket_base, row_ptr, dinv, csr_src, N);

    // 2. project + pre-scale: y0' = dinv * (x @ W^T)   (bf16)
    gemm_kernel<<<(N + 63) / 64, 256, 0, stream>>>(x, W, dinv, y0b, N);

    // 3. hop 1: y1' = dinv^2 * (y0'[row] + sum y0'[src])
    gather_kernel<0><<<(N + 3) / 4, 256, 0, stream>>>(row_ptr, csr_src, dinv, y0b, b,
                                                      y1b, nullptr, nullptr, N);

    // 4. hop 2 + bias + log_softmax, fused
    gather_kernel<1><<<(N + 3) / 4, 256, 0, stream>>>(row_ptr, csr_src, dinv, y1b, b,
                                                      nullptr, out_ptr, emb_ptr, N);
}